// Round 2
// baseline (220.605 us; speedup 1.0000x reference)
//
#include <hip/hip_runtime.h>
#include <math.h>

typedef __bf16 bf16_t;
typedef __bf16 bf16x4 __attribute__((ext_vector_type(4)));
typedef __bf16 bf16x8 __attribute__((ext_vector_type(8)));
typedef float f32x4 __attribute__((ext_vector_type(4)));

#define DIMC 256
#define HEADS 4
#define HDIM 64
#define HID 768
#define NB 8
#define NN 4096
#define ROWS (NB*NN)   /* 32768 */
#define NCHUNK 16

// ---------------- prep: x -> bf16 ----------------
__global__ __launch_bounds__(256) void prep_x_kernel(const float* __restrict__ x,
                                                     bf16_t* __restrict__ xb) {
  int i = (blockIdx.x * 256 + threadIdx.x) * 8;
  f32x4 a = *(const f32x4*)(x + i);
  f32x4 b = *(const f32x4*)(x + i + 4);
  bf16x8 o;
  o[0] = (bf16_t)a[0]; o[1] = (bf16_t)a[1]; o[2] = (bf16_t)a[2]; o[3] = (bf16_t)a[3];
  o[4] = (bf16_t)b[0]; o[5] = (bf16_t)b[1]; o[6] = (bf16_t)b[2]; o[7] = (bf16_t)b[3];
  *(bf16x8*)(xb + i) = o;
}

// ---------------- prep: transpose weight [K][Nw] -> bf16 [Nw][K], tiled ----------------
__global__ __launch_bounds__(256) void transpose_w_kernel(const float* __restrict__ w,
                                                          bf16_t* __restrict__ wt,
                                                          int K, int Nw) {
  __shared__ float tile[32][33];
  const int bx = blockIdx.x, by = blockIdx.y;  // n-tile, k-tile
  const int t = threadIdx.x;
#pragma unroll
  for (int i = 0; i < 4; ++i) {
    int idx = i * 256 + t;
    int r = idx >> 5, cc = idx & 31;  // r: k, cc: n
    tile[r][cc] = w[(size_t)(by * 32 + r) * Nw + bx * 32 + cc];
  }
  __syncthreads();
#pragma unroll
  for (int i = 0; i < 4; ++i) {
    int idx = i * 256 + t;
    int n_ = idx >> 5, kk = idx & 31;
    wt[(size_t)(bx * 32 + n_) * K + by * 32 + kk] = (bf16_t)tile[kk][n_];
  }
}

__device__ __forceinline__ float gelu_exact(float v) {
  return 0.5f * v * (1.0f + erff(v * 0.70710678118654752f));
}

// ---------------- bf16 MFMA GEMM: C[M,N] = A[M,K] * BT[N,K]^T (+epilogue) ----------------
// Operands SWAPPED in the mfma so each thread's 4 acc regs walk consecutive N:
//   thread holds rows m0+wr*64+mi*16+lr, cols n0+wc*64+ni*16+lk*4+{0..3}.
// EPI 0: out bf16 = acc + bias
// EPI 1: out bf16 = gelu(acc + bias)
// EPI 2: out f32  = acc + bias + resid(bf16)
template <int EPI>
__global__ __launch_bounds__(256)
void gemm_kernel(const bf16_t* __restrict__ A, const bf16_t* __restrict__ BT,
                 const float* __restrict__ bias, void* __restrict__ outp,
                 const bf16_t* __restrict__ resid, int N, int K) {
  __shared__ __align__(16) bf16_t ldsA[2][512 * 8];
  __shared__ __align__(16) bf16_t ldsB[2][512 * 8];
  const int tid = threadIdx.x;
  const int m0 = blockIdx.y * 128, n0 = blockIdx.x * 128;
  const int lane = tid & 63, w = tid >> 6;
  const int wr = w >> 1, wc = w & 1;
  const int lr = lane & 15, lk = lane >> 4;

  f32x4 acc[4][4] = {};
  const int ksteps = K >> 5;

  auto stage = [&](int buf, int ks) {
#pragma unroll
    for (int i = 0; i < 2; ++i) {
      int p = i * 256 + tid;
      int row = p & 127, kc = p >> 7;
      const bf16_t* ga = A + (size_t)(m0 + row) * K + ks * 32 + kc * 8;
      __builtin_amdgcn_global_load_lds(
          (const __attribute__((address_space(1))) void*)ga,
          (__attribute__((address_space(3))) void*)&ldsA[buf][p * 8], 16, 0, 0);
      const bf16_t* gb = BT + (size_t)(n0 + row) * K + ks * 32 + kc * 8;
      __builtin_amdgcn_global_load_lds(
          (const __attribute__((address_space(1))) void*)gb,
          (__attribute__((address_space(3))) void*)&ldsB[buf][p * 8], 16, 0, 0);
    }
  };

  auto compute = [&](int buf) {
    const bf16x8* pA = (const bf16x8*)&ldsA[buf][0];
    const bf16x8* pB = (const bf16x8*)&ldsB[buf][0];
    bf16x8 af[4], bfr[4];
#pragma unroll
    for (int mi = 0; mi < 4; ++mi) af[mi] = pA[lk * 128 + wr * 64 + mi * 16 + lr];
#pragma unroll
    for (int ni = 0; ni < 4; ++ni) bfr[ni] = pB[lk * 128 + wc * 64 + ni * 16 + lr];
#pragma unroll
    for (int mi = 0; mi < 4; ++mi)
#pragma unroll
      for (int ni = 0; ni < 4; ++ni)
        acc[mi][ni] = __builtin_amdgcn_mfma_f32_16x16x32_bf16(bfr[ni], af[mi],
                                                              acc[mi][ni], 0, 0, 0);
  };

  stage(0, 0);
  __syncthreads();
  int cur = 0;
  for (int ks = 0; ks < ksteps - 1; ++ks) {
    stage(cur ^ 1, ks + 1);
    compute(cur);
    __syncthreads();
    cur ^= 1;
  }
  compute(cur);

  // epilogue: thread -> row m0+wr*64+mi*16+lr, 4 consecutive cols per acc reg
#pragma unroll
  for (int mi = 0; mi < 4; ++mi) {
    const int row = m0 + wr * 64 + mi * 16 + lr;
#pragma unroll
    for (int ni = 0; ni < 4; ++ni) {
      const int n4 = n0 + wc * 64 + ni * 16 + lk * 4;
      f32x4 v = acc[mi][ni];
      f32x4 bs = *(const f32x4*)(bias + n4);
      v += bs;
      size_t off = (size_t)row * N + n4;
      if (EPI == 2) {
        bf16x4 rz = *(const bf16x4*)(resid + off);
        f32x4 o;
#pragma unroll
        for (int r = 0; r < 4; ++r) o[r] = v[r] + (float)rz[r];
        *(f32x4*)((float*)outp + off) = o;
      } else {
        bf16x4 o;
#pragma unroll
        for (int r = 0; r < 4; ++r) {
          float val = v[r];
          if (EPI == 1) val = gelu_exact(val);
          o[r] = (bf16_t)val;
        }
        *(bf16x4*)((bf16_t*)outp + off) = o;
      }
    }
  }
}

// ---------------- attention: partial K^T V over N-chunks ----------------
__global__ __launch_bounds__(256)
void attn_kv_kernel(const bf16_t* __restrict__ qkv, float* __restrict__ part) {
  const int bh = blockIdx.x, chunk = blockIdx.y;
  const int b = bh >> 2, h = bh & 3;
  __shared__ __align__(16) float kl[32][68];
  __shared__ __align__(16) float vl[32][68];
  const int tid = threadIdx.x;
  const int dg = tid >> 4, eg = tid & 15;
  f32x4 acc[4] = {};
  const int rows_per_chunk = NN / NCHUNK;  // 256
  const int n00 = chunk * rows_per_chunk;
  const int srow = tid >> 3, spk = tid & 7;
  for (int t = 0; t < rows_per_chunk / 32; ++t) {
    int n0 = n00 + t * 32;
    {
      const bf16x8 k8 = *(const bf16x8*)(qkv + (size_t)(b * NN + n0 + srow) * HID + 256 + h * 64 + spk * 8);
      const bf16x8 v8 = *(const bf16x8*)(qkv + (size_t)(b * NN + n0 + srow) * HID + 512 + h * 64 + spk * 8);
#pragma unroll
      for (int j = 0; j < 8; ++j) kl[srow][spk * 8 + j] = (float)k8[j];
#pragma unroll
      for (int j = 0; j < 8; ++j) vl[srow][spk * 8 + j] = (float)v8[j];
    }
    __syncthreads();
#pragma unroll 8
    for (int n = 0; n < 32; ++n) {
      f32x4 k4 = *(const f32x4*)&kl[n][dg * 4];
      f32x4 v4 = *(const f32x4*)&vl[n][eg * 4];
#pragma unroll
      for (int i = 0; i < 4; ++i) acc[i] += k4[i] * v4;
    }
    __syncthreads();
  }
  float* dst = part + (size_t)(chunk * 32 + bh) * 4096;
#pragma unroll
  for (int i = 0; i < 4; ++i)
    *(f32x4*)&dst[(dg * 4 + i) * 64 + eg * 4] = acc[i];
}

// ---------------- attention: reduce partials + scale + softmax over e ----------------
__global__ __launch_bounds__(256)
void attn_softmax_kernel(const float* __restrict__ part, float* __restrict__ attn) {
  const int bh = blockIdx.x;
  const int tid = threadIdx.x;
  const int dg = tid >> 4, eg = tid & 15;
  f32x4 s[4] = {};
  for (int c = 0; c < NCHUNK; ++c) {
    const float* src = part + (size_t)(c * 32 + bh) * 4096;
#pragma unroll
    for (int i = 0; i < 4; ++i) s[i] += *(const f32x4*)&src[(dg * 4 + i) * 64 + eg * 4];
  }
  float* dst = attn + (size_t)bh * 4096;
#pragma unroll
  for (int i = 0; i < 4; ++i) {
    f32x4 l = s[i] * 0.125f;  // k-scale = 1/sqrt(64)
    float m = fmaxf(fmaxf(l[0], l[1]), fmaxf(l[2], l[3]));
#pragma unroll
    for (int msk = 1; msk < 16; msk <<= 1) m = fmaxf(m, __shfl_xor(m, msk));
    f32x4 p;
    float sum = 0.f;
#pragma unroll
    for (int j = 0; j < 4; ++j) { p[j] = expf(l[j] - m); sum += p[j]; }
#pragma unroll
    for (int msk = 1; msk < 16; msk <<= 1) sum += __shfl_xor(sum, msk);
    p *= (1.0f / sum);
    *(f32x4*)&dst[(dg * 4 + i) * 64 + eg * 4] = p;
  }
}

// ---------------- xf = Q attn^T, x2 = x + xf (bf16), hln = LN(x2) ----------------
// 32 rows/block; one 64-wide shuffle reduce per row batched 4 at a time,
// one barrier per 4-row group, per-group red slots (no WAR barrier).
__global__ __launch_bounds__(256)
void xf_ln2_kernel(const bf16_t* __restrict__ qkv, const float* __restrict__ attn,
                   const float* __restrict__ x, bf16_t* __restrict__ x2,
                   bf16_t* __restrict__ hln, const float* __restrict__ gamma,
                   const float* __restrict__ beta) {
  const int row0 = blockIdx.x * 32;
  const int b = row0 >> 12;
  const int tid = threadIdx.x;
  const int c = tid, h = c >> 6;
  const int w = tid >> 6, lane = tid & 63;

  f32x4 arow[16];
  const float* ap = attn + ((size_t)(b * 4 + h) * 64 + (c & 63)) * 64;
#pragma unroll
  for (int s = 0; s < 16; ++s) arow[s] = *(const f32x4*)&ap[s * 4];

  __shared__ __align__(16) bf16_t ql[32][256];
  __shared__ float red[8][4][4][2];
#pragma unroll
  for (int i = 0; i < 4; ++i) {
    int g = i * 256 + tid;
    int r = g >> 5, o8 = g & 31;
    *(bf16x8*)&ql[r][o8 * 8] = *(const bf16x8*)(qkv + (size_t)(row0 + r) * HID + o8 * 8);
  }
  __syncthreads();

  const float gv = gamma[c], bv = beta[c];
  for (int gg = 0; gg < 8; ++gg) {
    float x2v[4], s1[4], s2[4];
#pragma unroll
    for (int j = 0; j < 4; ++j) {
      const int r = gg * 4 + j;
      float xf = 0.f;
#pragma unroll
      for (int s = 0; s < 16; ++s) {
        // wave-uniform broadcast read of q[row][h*64 + s*4 .. +3]
        uint2 u = *(const uint2*)&ql[r][h * 64 + s * 4];
        float q0 = __uint_as_float(u.x << 16);
        float q1 = __uint_as_float(u.x & 0xffff0000u);
        float q2 = __uint_as_float(u.y << 16);
        float q3 = __uint_as_float(u.y & 0xffff0000u);
        f32x4 a4 = arow[s];
        xf += a4[0] * q0 + a4[1] * q1 + a4[2] * q2 + a4[3] * q3;
      }
      size_t off = (size_t)(row0 + r) * DIMC + c;
      float xv = x[off] + xf;
      x2v[j] = xv; s1[j] = xv; s2[j] = xv * xv;
    }
#pragma unroll
    for (int m = 1; m < 64; m <<= 1) {
#pragma unroll
      for (int j = 0; j < 4; ++j) {
        s1[j] += __shfl_xor(s1[j], m);
        s2[j] += __shfl_xor(s2[j], m);
      }
    }
    if (lane == 0) {
#pragma unroll
      for (int j = 0; j < 4; ++j) { red[gg][w][j][0] = s1[j]; red[gg][w][j][1] = s2[j]; }
    }
    __syncthreads();
#pragma unroll
    for (int j = 0; j < 4; ++j) {
      float t1 = red[gg][0][j][0] + red[gg][1][j][0] + red[gg][2][j][0] + red[gg][3][j][0];
      float t2 = red[gg][0][j][1] + red[gg][1][j][1] + red[gg][2][j][1] + red[gg][3][j][1];
      float mu = t1 * (1.0f / 256.0f);
      float var = t2 * (1.0f / 256.0f) - mu * mu;
      float rs = rsqrtf(var + 1e-5f);
      size_t off = (size_t)(row0 + gg * 4 + j) * DIMC + c;
      x2[off] = (bf16_t)x2v[j];
      hln[off] = (bf16_t)((x2v[j] - mu) * rs * gv + bv);
    }
  }
}

extern "C" void kernel_launch(void* const* d_in, const int* in_sizes, int n_in,
                              void* d_out, int out_size, void* d_ws, size_t ws_size,
                              hipStream_t stream) {
  const float* x      = (const float*)d_in[0];
  const float* w_qkv  = (const float*)d_in[1];
  const float* b_qkv  = (const float*)d_in[2];
  const float* norm_g = (const float*)d_in[3];
  const float* norm_b = (const float*)d_in[4];
  const float* w_fc1  = (const float*)d_in[5];
  const float* b_fc1  = (const float*)d_in[6];
  const float* w_fc2  = (const float*)d_in[7];
  const float* b_fc2  = (const float*)d_in[8];

  char* ws = (char*)d_ws;
  size_t off = 0;
  bf16_t* qkv   = (bf16_t*)(ws + off); off += (size_t)ROWS * HID * 2;          // 50.3 MB (reused as mid)
  bf16_t* mid   = qkv;
  bf16_t* xb    = (bf16_t*)(ws + off); off += (size_t)ROWS * DIMC * 2;         // 16.8 MB (reused as hln)
  bf16_t* hln   = xb;
  float*  part  = (float*)(ws + off);  off += (size_t)NCHUNK * 32 * 4096 * 4;  // 8.4 MB
  float*  attn  = (float*)(ws + off);  off += (size_t)32 * 4096 * 4;           // 0.5 MB
  bf16_t* x2b   = (bf16_t*)(ws + off); off += (size_t)ROWS * DIMC * 2;         // 16.8 MB
  bf16_t* wqkvT = (bf16_t*)(ws + off); off += (size_t)768 * 256 * 2;
  bf16_t* wfc1T = (bf16_t*)(ws + off); off += (size_t)768 * 256 * 2;
  bf16_t* wfc2T = (bf16_t*)(ws + off); off += (size_t)256 * 768 * 2;

  prep_x_kernel<<<(ROWS * DIMC) / (256 * 8), 256, 0, stream>>>(x, xb);
  transpose_w_kernel<<<dim3(24, 8), 256, 0, stream>>>(w_qkv, wqkvT, 256, 768);
  transpose_w_kernel<<<dim3(24, 8), 256, 0, stream>>>(w_fc1, wfc1T, 256, 768);
  transpose_w_kernel<<<dim3(8, 24), 256, 0, stream>>>(w_fc2, wfc2T, 768, 256);

  // qkv = x @ w_qkv + b_qkv            [32768 x 768], K=256
  gemm_kernel<0><<<dim3(6, 256), 256, 0, stream>>>(xb, wqkvT, b_qkv, qkv, nullptr, 768, 256);
  // attn partials + softmax
  attn_kv_kernel<<<dim3(32, NCHUNK), 256, 0, stream>>>(qkv, part);
  attn_softmax_kernel<<<32, 256, 0, stream>>>(part, attn);
  // xf + residual + layernorm
  xf_ln2_kernel<<<ROWS / 32, 256, 0, stream>>>(qkv, attn, x, x2b, hln, norm_g, norm_b);
  // mid = gelu(hln @ w_fc1 + b_fc1)    [32768 x 768], K=256
  gemm_kernel<1><<<dim3(6, 256), 256, 0, stream>>>(hln, wfc1T, b_fc1, mid, nullptr, 768, 256);
  // out = x2 + mid @ w_fc2 + b_fc2     [32768 x 256], K=768
  gemm_kernel<2><<<dim3(2, 256), 256, 0, stream>>>(mid, wfc2T, b_fc2, d_out, x2b, 256, 768);
}

// Round 3
// 179.767 us; speedup vs baseline: 1.2272x; 1.2272x over previous
//
#include <hip/hip_runtime.h>
#include <math.h>

typedef __bf16 bf16_t;
typedef __bf16 bf16x4 __attribute__((ext_vector_type(4)));
typedef __bf16 bf16x8 __attribute__((ext_vector_type(8)));
typedef float f32x4 __attribute__((ext_vector_type(4)));

#define DIMC 256
#define HID 768
#define NB 8
#define NN 4096
#define ROWS (NB*NN)   /* 32768 */
#define NCHUNK 16

#define AS1 __attribute__((address_space(1)))
#define AS3 __attribute__((address_space(3)))

__device__ __forceinline__ void gll16(const bf16_t* src, void* lds) {
  __builtin_amdgcn_global_load_lds((const AS1 void*)src, (AS3 void*)lds, 16, 0, 0);
}

// ---------------- prep: x -> bf16 ----------------
__global__ __launch_bounds__(256) void prep_x_kernel(const float* __restrict__ x,
                                                     bf16_t* __restrict__ xb) {
  int i = (blockIdx.x * 256 + threadIdx.x) * 8;
  f32x4 a = *(const f32x4*)(x + i);
  f32x4 b = *(const f32x4*)(x + i + 4);
  bf16x8 o;
  o[0] = (bf16_t)a[0]; o[1] = (bf16_t)a[1]; o[2] = (bf16_t)a[2]; o[3] = (bf16_t)a[3];
  o[4] = (bf16_t)b[0]; o[5] = (bf16_t)b[1]; o[6] = (bf16_t)b[2]; o[7] = (bf16_t)b[3];
  *(bf16x8*)(xb + i) = o;
}

// ---------------- prep: transpose weight [K][Nw] -> bf16 [Nw][K], tiled ----------------
__global__ __launch_bounds__(256) void transpose_w_kernel(const float* __restrict__ w,
                                                          bf16_t* __restrict__ wt,
                                                          int K, int Nw) {
  __shared__ float tile[32][33];
  const int bx = blockIdx.x, by = blockIdx.y;
  const int t = threadIdx.x;
#pragma unroll
  for (int i = 0; i < 4; ++i) {
    int idx = i * 256 + t;
    int r = idx >> 5, cc = idx & 31;
    tile[r][cc] = w[(size_t)(by * 32 + r) * Nw + bx * 32 + cc];
  }
  __syncthreads();
#pragma unroll
  for (int i = 0; i < 4; ++i) {
    int idx = i * 256 + t;
    int n_ = idx >> 5, kk = idx & 31;
    wt[(size_t)(bx * 32 + n_) * K + by * 32 + kk] = (bf16_t)tile[kk][n_];
  }
}

__device__ __forceinline__ float gelu_exact(float v) {
  return 0.5f * v * (1.0f + erff(v * 0.70710678118654752f));
}

// ============ A-resident GEMM: C[M,768] = A[M,256] @ BT[768,256]^T + bias ============
// Block: 128 rows, A fully in LDS (64KB, XOR-swizzled), loop 12 panels of 64 cols,
// B double-buffered (2x32KB), counted vmcnt, A-frags hoisted to 128 VGPRs.
// EPI 0: bf16 out = acc+bias ; EPI 1: bf16 out = gelu(acc+bias)
template <int EPI>
__global__ __launch_bounds__(256, 1)
void gemm_ares_kernel(const bf16_t* __restrict__ A, const bf16_t* __restrict__ BT,
                      const float* __restrict__ bias, bf16_t* __restrict__ outp) {
  __shared__ __align__(16) unsigned char smem[131072];  // A: 0..65536, B: 2x32768
  const int tid = threadIdx.x;
  const int m0 = blockIdx.x * 128;
  const int lane = tid & 63, w = tid >> 6;
  const int wr = w >> 1, wc = w & 1;
  const int lr = lane & 15, lk = lane >> 4;

  // ---- stage A (full 128x256 tile), coalesced: wave = 2 full 512B rows ----
#pragma unroll
  for (int i = 0; i < 16; ++i) {
    int idx = i * 256 + tid;            // 0..4095
    int row = idx >> 5, pk = idx & 31;
    gll16(A + (size_t)(m0 + row) * 256 + ((pk ^ (row & 7)) * 8), smem + idx * 16);
  }
  // ---- stage B panel 0 and 1 ----
#pragma unroll
  for (int np = 0; np < 2; ++np) {
#pragma unroll
    for (int i = 0; i < 8; ++i) {
      int idx = i * 256 + tid;          // 0..2047
      int row = idx >> 5, pk = idx & 31;
      gll16(BT + (size_t)(np * 64 + row) * 256 + ((pk ^ (row & 7)) * 8),
            smem + 65536 + np * 32768 + idx * 16);
    }
  }
  asm volatile("s_waitcnt vmcnt(8)" ::: "memory");   // A + B0 done, B1 in flight
  __builtin_amdgcn_s_barrier();

  // ---- hoist A fragments: af[mi][kk], 32 x ds_read_b128 ----
  bf16x8 af[4][8];
#pragma unroll
  for (int mi = 0; mi < 4; ++mi) {
#pragma unroll
    for (int kk = 0; kk < 8; ++kk) {
      int row = wr * 64 + mi * 16 + lr;
      af[mi][kk] = *(const bf16x8*)(smem + row * 512 + (((kk * 4 + lk) ^ (row & 7)) * 16));
    }
  }

  f32x4 acc[4][2] = {};
#pragma unroll
  for (int np = 0; np < 12; ++np) {
    const unsigned char* bbase = smem + 65536 + (np & 1) * 32768;
    // ---- compute panel np ----
#pragma unroll
    for (int kk = 0; kk < 8; ++kk) {
      int r0 = wc * 32 + lr, r1 = wc * 32 + 16 + lr;
      bf16x8 b0 = *(const bf16x8*)(bbase + r0 * 512 + (((kk * 4 + lk) ^ (r0 & 7)) * 16));
      bf16x8 b1 = *(const bf16x8*)(bbase + r1 * 512 + (((kk * 4 + lk) ^ (r1 & 7)) * 16));
#pragma unroll
      for (int mi = 0; mi < 4; ++mi) {
        acc[mi][0] = __builtin_amdgcn_mfma_f32_16x16x32_bf16(b0, af[mi][kk], acc[mi][0], 0, 0, 0);
        acc[mi][1] = __builtin_amdgcn_mfma_f32_16x16x32_bf16(b1, af[mi][kk], acc[mi][1], 0, 0, 0);
      }
    }
    __builtin_amdgcn_s_barrier();        // all waves done reading buf np&1
    if (np + 2 < 12) {
#pragma unroll
      for (int i = 0; i < 8; ++i) {
        int idx = i * 256 + tid;
        int row = idx >> 5, pk = idx & 31;
        gll16(BT + (size_t)((np + 2) * 64 + row) * 256 + ((pk ^ (row & 7)) * 8),
              smem + 65536 + (np & 1) * 32768 + idx * 16);
      }
    }
    // ---- epilogue panel np (8 x 8B stores; retire during next compute) ----
#pragma unroll
    for (int mi = 0; mi < 4; ++mi) {
      int row = m0 + wr * 64 + mi * 16 + lr;
#pragma unroll
      for (int ni = 0; ni < 2; ++ni) {
        int col = np * 64 + wc * 32 + ni * 16 + lk * 4;
        f32x4 v = acc[mi][ni] + *(const f32x4*)(bias + col);
        bf16x4 o;
#pragma unroll
        for (int r = 0; r < 4; ++r) {
          float val = v[r];
          if (EPI == 1) val = gelu_exact(val);
          o[r] = (bf16_t)val;
        }
        *(bf16x4*)(outp + (size_t)row * 768 + col) = o;
        acc[mi][ni] = (f32x4){0.f, 0.f, 0.f, 0.f};
      }
    }
    if (np < 11) {
      if (np <= 9) asm volatile("s_waitcnt vmcnt(24)" ::: "memory");  // B(np+1) done
      else         asm volatile("s_waitcnt vmcnt(16)" ::: "memory");
      __builtin_amdgcn_s_barrier();
    }
  }
}

// ============ fc2: out[M,256] = mid[M,768] @ wT[256,768]^T + bias + resid ============
// Block: 64 rows; A(mid)-chunks (BK=128) dbuf in LDS; B-frags streamed L2->reg.
__global__ __launch_bounds__(256, 2)
void fc2_kernel(const bf16_t* __restrict__ mid, const bf16_t* __restrict__ wT,
                const float* __restrict__ bias, const bf16_t* __restrict__ resid,
                float* __restrict__ outp) {
  __shared__ __align__(16) unsigned char smem[2][16384];  // 64 rows x 128k x 2B
  const int tid = threadIdx.x;
  const int m0 = blockIdx.x * 64;
  const int lane = tid & 63, w = tid >> 6;
  const int lr = lane & 15, lk = lane >> 4;

  auto stageA = [&](int c, int buf) {
#pragma unroll
    for (int i = 0; i < 4; ++i) {
      int idx = i * 256 + tid;          // 0..1023
      int row = idx >> 4, pk = idx & 15;
      gll16(mid + (size_t)(m0 + row) * 768 + c * 128 + ((pk ^ (row & 7)) * 8),
            smem[buf] + idx * 16);
    }
  };

  stageA(0, 0);
  stageA(1, 1);
  asm volatile("s_waitcnt vmcnt(4)" ::: "memory");
  __builtin_amdgcn_s_barrier();

  f32x4 acc[4][4] = {};
#pragma unroll
  for (int c = 0; c < 6; ++c) {
    // B fragments for this chunk (L2-resident weights)
    bf16x8 bf[4][4];
#pragma unroll
    for (int nf = 0; nf < 4; ++nf)
#pragma unroll
      for (int kq = 0; kq < 4; ++kq)
        bf[nf][kq] = *(const bf16x8*)(wT + (size_t)(w * 64 + nf * 16 + lr) * 768 +
                                      c * 128 + kq * 32 + lk * 8);
    asm volatile("s_waitcnt vmcnt(0)" ::: "memory");
    __builtin_amdgcn_s_barrier();
#pragma unroll
    for (int kq = 0; kq < 4; ++kq) {
#pragma unroll
      for (int mi = 0; mi < 4; ++mi) {
        int row = mi * 16 + lr;
        bf16x8 a8 = *(const bf16x8*)(smem[c & 1] + row * 256 + (((kq * 4 + lk) ^ (row & 7)) * 16));
#pragma unroll
        for (int nf = 0; nf < 4; ++nf)
          acc[mi][nf] = __builtin_amdgcn_mfma_f32_16x16x32_bf16(bf[nf][kq], a8, acc[mi][nf], 0, 0, 0);
      }
    }
    __builtin_amdgcn_s_barrier();
    if (c + 2 < 6) stageA(c + 2, c & 1);
  }
  // epilogue
#pragma unroll
  for (int mi = 0; mi < 4; ++mi) {
    int row = m0 + mi * 16 + lr;
#pragma unroll
    for (int nf = 0; nf < 4; ++nf) {
      int col = w * 64 + nf * 16 + lk * 4;
      size_t off = (size_t)row * 256 + col;
      f32x4 v = acc[mi][nf] + *(const f32x4*)(bias + col);
      bf16x4 rz = *(const bf16x4*)(resid + off);
      f32x4 o;
#pragma unroll
      for (int r = 0; r < 4; ++r) o[r] = v[r] + (float)rz[r];
      *(f32x4*)(outp + off) = o;
    }
  }
}

// ---------------- attention: partial K^T V over N-chunks (VALU) ----------------
__global__ __launch_bounds__(256)
void attn_kv_kernel(const bf16_t* __restrict__ qkv, float* __restrict__ part) {
  const int bh = blockIdx.x, chunk = blockIdx.y;
  const int b = bh >> 2, h = bh & 3;
  __shared__ __align__(16) float kl[32][68];
  __shared__ __align__(16) float vl[32][68];
  const int tid = threadIdx.x;
  const int dg = tid >> 4, eg = tid & 15;
  f32x4 acc[4] = {};
  const int n00 = chunk * (NN / NCHUNK);
  const int srow = tid >> 3, spk = tid & 7;
  for (int t = 0; t < (NN / NCHUNK) / 32; ++t) {
    int n0 = n00 + t * 32;
    {
      const bf16x8 k8 = *(const bf16x8*)(qkv + (size_t)(b * NN + n0 + srow) * HID + 256 + h * 64 + spk * 8);
      const bf16x8 v8 = *(const bf16x8*)(qkv + (size_t)(b * NN + n0 + srow) * HID + 512 + h * 64 + spk * 8);
#pragma unroll
      for (int j = 0; j < 8; ++j) kl[srow][spk * 8 + j] = (float)k8[j];
#pragma unroll
      for (int j = 0; j < 8; ++j) vl[srow][spk * 8 + j] = (float)v8[j];
    }
    __syncthreads();
#pragma unroll 8
    for (int n = 0; n < 32; ++n) {
      f32x4 k4 = *(const f32x4*)&kl[n][dg * 4];
      f32x4 v4 = *(const f32x4*)&vl[n][eg * 4];
#pragma unroll
      for (int i = 0; i < 4; ++i) acc[i] += k4[i] * v4;
    }
    __syncthreads();
  }
  float* dst = part + (size_t)(chunk * 32 + bh) * 4096;
#pragma unroll
  for (int i = 0; i < 4; ++i)
    *(f32x4*)&dst[(dg * 4 + i) * 64 + eg * 4] = acc[i];
}

// ---------------- reduce partials + scale + softmax -> bf16 attn ----------------
__global__ __launch_bounds__(256)
void attn_softmax_kernel(const float* __restrict__ part, bf16_t* __restrict__ attnb) {
  const int bh = blockIdx.x;
  const int tid = threadIdx.x;
  const int dg = tid >> 4, eg = tid & 15;
  f32x4 s[4] = {};
  for (int c = 0; c < NCHUNK; ++c) {
    const float* src = part + (size_t)(c * 32 + bh) * 4096;
#pragma unroll
    for (int i = 0; i < 4; ++i) s[i] += *(const f32x4*)&src[(dg * 4 + i) * 64 + eg * 4];
  }
  bf16_t* dst = attnb + (size_t)bh * 4096;
#pragma unroll
  for (int i = 0; i < 4; ++i) {
    f32x4 l = s[i] * 0.125f;
    float m = fmaxf(fmaxf(l[0], l[1]), fmaxf(l[2], l[3]));
#pragma unroll
    for (int msk = 1; msk < 16; msk <<= 1) m = fmaxf(m, __shfl_xor(m, msk));
    f32x4 p;
    float sum = 0.f;
#pragma unroll
    for (int j = 0; j < 4; ++j) { p[j] = expf(l[j] - m); sum += p[j]; }
#pragma unroll
    for (int msk = 1; msk < 16; msk <<= 1) sum += __shfl_xor(sum, msk);
    float inv = 1.0f / sum;
    bf16x4 o;
#pragma unroll
    for (int j = 0; j < 4; ++j) o[j] = (bf16_t)(p[j] * inv);
    *(bf16x4*)&dst[(dg * 4 + i) * 64 + eg * 4] = o;
  }
}

// ---------------- xf = Q @ attn^T (MFMA), x2 = xb + xf, hln = LN(x2) ----------------
// Block: 64 rows; wave w = head w. Q staged in LDS (32KB, swizzled).
__global__ __launch_bounds__(256, 2)
void xf_ln_mfma_kernel(const bf16_t* __restrict__ qkv, const bf16_t* __restrict__ attnb,
                       const bf16_t* __restrict__ xb, bf16_t* __restrict__ x2b,
                       bf16_t* __restrict__ hln, const float* __restrict__ gamma,
                       const float* __restrict__ beta) {
  __shared__ __align__(16) unsigned char qs[32768];
  __shared__ float red[4][4][16][2];
  const int tid = threadIdx.x;
  const int row0 = blockIdx.x * 64;
  const int b = row0 >> 12;
  const int lane = tid & 63, h = tid >> 6;
  const int lr = lane & 15, lk = lane >> 4;

  // stage q rows (cols 0..255 of qkv rows): wave = 2 coalesced 512B segments
#pragma unroll
  for (int i = 0; i < 8; ++i) {
    int idx = i * 256 + tid;            // 0..2047
    int row = idx >> 5, pk = idx & 31;
    gll16(qkv + (size_t)(row0 + row) * HID + ((pk ^ (row & 7)) * 8), qs + idx * 16);
  }
  asm volatile("s_waitcnt vmcnt(0)" ::: "memory");
  __builtin_amdgcn_s_barrier();

  // A-frags (q): lane lr = row; elems = e of head h
  bf16x8 af[4][2];
#pragma unroll
  for (int mi = 0; mi < 4; ++mi)
#pragma unroll
    for (int kk = 0; kk < 2; ++kk) {
      int row = mi * 16 + lr;
      int pk = h * 8 + kk * 4 + lk;
      af[mi][kk] = *(const bf16x8*)(qs + row * 512 + ((pk ^ (row & 7)) * 16));
    }
  // B-frags (attn): lane lr = out-col d; elems = e
  bf16x8 bfr[4][2];
#pragma unroll
  for (int nf = 0; nf < 4; ++nf)
#pragma unroll
    for (int kk = 0; kk < 2; ++kk)
      bfr[nf][kk] = *(const bf16x8*)(attnb + (size_t)(b * 4 + h) * 4096 +
                                     (nf * 16 + lr) * 64 + kk * 32 + lk * 8);
  f32x4 acc[4][4] = {};
#pragma unroll
  for (int kk = 0; kk < 2; ++kk)
#pragma unroll
    for (int mi = 0; mi < 4; ++mi)
#pragma unroll
      for (int nf = 0; nf < 4; ++nf)
        acc[mi][nf] = __builtin_amdgcn_mfma_f32_16x16x32_bf16(bfr[nf][kk], af[mi][kk], acc[mi][nf], 0, 0, 0);

  // x2 = xb + xf; write x2b; partial sums for LN
  float ps[4], pq[4];
#pragma unroll
  for (int mi = 0; mi < 4; ++mi) {
    ps[mi] = 0.f; pq[mi] = 0.f;
    int row = row0 + mi * 16 + lr;
#pragma unroll
    for (int nf = 0; nf < 4; ++nf) {
      int col = h * 64 + nf * 16 + lk * 4;
      size_t off = (size_t)row * DIMC + col;
      bf16x4 xv = *(const bf16x4*)(xb + off);
      f32x4 x2;
#pragma unroll
      for (int r = 0; r < 4; ++r) {
        x2[r] = acc[mi][nf][r] + (float)xv[r];
        ps[mi] += x2[r]; pq[mi] += x2[r] * x2[r];
      }
      acc[mi][nf] = x2;  // keep for hln
      bf16x4 o;
#pragma unroll
      for (int r = 0; r < 4; ++r) o[r] = (bf16_t)x2[r];
      *(bf16x4*)(x2b + off) = o;
    }
#pragma unroll
    for (int m = 16; m < 64; m <<= 1) {
      ps[mi] += __shfl_xor(ps[mi], m);
      pq[mi] += __shfl_xor(pq[mi], m);
    }
  }
  if (lk == 0) {
#pragma unroll
    for (int mi = 0; mi < 4; ++mi) { red[h][mi][lr][0] = ps[mi]; red[h][mi][lr][1] = pq[mi]; }
  }
  __builtin_amdgcn_s_barrier();
#pragma unroll
  for (int mi = 0; mi < 4; ++mi) {
    float t1 = red[0][mi][lr][0] + red[1][mi][lr][0] + red[2][mi][lr][0] + red[3][mi][lr][0];
    float t2 = red[0][mi][lr][1] + red[1][mi][lr][1] + red[2][mi][lr][1] + red[3][mi][lr][1];
    float mu = t1 * (1.0f / 256.0f);
    float var = t2 * (1.0f / 256.0f) - mu * mu;
    float rs = rsqrtf(var + 1e-5f);
    int row = row0 + mi * 16 + lr;
#pragma unroll
    for (int nf = 0; nf < 4; ++nf) {
      int col = h * 64 + nf * 16 + lk * 4;
      f32x4 g4 = *(const f32x4*)(gamma + col);
      f32x4 b4 = *(const f32x4*)(beta + col);
      bf16x4 o;
#pragma unroll
      for (int r = 0; r < 4; ++r)
        o[r] = (bf16_t)((acc[mi][nf][r] - mu) * rs * g4[r] + b4[r]);
      *(bf16x4*)(hln + (size_t)row * DIMC + col) = o;
    }
  }
}

extern "C" void kernel_launch(void* const* d_in, const int* in_sizes, int n_in,
                              void* d_out, int out_size, void* d_ws, size_t ws_size,
                              hipStream_t stream) {
  const float* x      = (const float*)d_in[0];
  const float* w_qkv  = (const float*)d_in[1];
  const float* b_qkv  = (const float*)d_in[2];
  const float* norm_g = (const float*)d_in[3];
  const float* norm_b = (const float*)d_in[4];
  const float* w_fc1  = (const float*)d_in[5];
  const float* b_fc1  = (const float*)d_in[6];
  const float* w_fc2  = (const float*)d_in[7];
  const float* b_fc2  = (const float*)d_in[8];

  char* ws = (char*)d_ws;
  size_t off = 0;
  bf16_t* qkv   = (bf16_t*)(ws + off); off += (size_t)ROWS * HID * 2;          // 50.3 MB (reused as mid)
  bf16_t* mid   = qkv;
  bf16_t* xb    = (bf16_t*)(ws + off); off += (size_t)ROWS * DIMC * 2;         // 16.8 MB
  bf16_t* hln   = (bf16_t*)(ws + off); off += (size_t)ROWS * DIMC * 2;         // 16.8 MB
  bf16_t* x2b   = (bf16_t*)(ws + off); off += (size_t)ROWS * DIMC * 2;         // 16.8 MB
  float*  part  = (float*)(ws + off);  off += (size_t)NCHUNK * 32 * 4096 * 4;  // 8.4 MB
  bf16_t* attnb = (bf16_t*)(ws + off); off += (size_t)32 * 4096 * 2;           // 0.26 MB
  bf16_t* wqkvT = (bf16_t*)(ws + off); off += (size_t)768 * 256 * 2;
  bf16_t* wfc1T = (bf16_t*)(ws + off); off += (size_t)768 * 256 * 2;
  bf16_t* wfc2T = (bf16_t*)(ws + off); off += (size_t)256 * 768 * 2;

  prep_x_kernel<<<(ROWS * DIMC) / (256 * 8), 256, 0, stream>>>(x, xb);
  transpose_w_kernel<<<dim3(24, 8), 256, 0, stream>>>(w_qkv, wqkvT, 256, 768);
  transpose_w_kernel<<<dim3(24, 8), 256, 0, stream>>>(w_fc1, wfc1T, 256, 768);
  transpose_w_kernel<<<dim3(8, 24), 256, 0, stream>>>(w_fc2, wfc2T, 768, 256);

  // qkv = x @ w_qkv + b_qkv    [32768 x 768]
  gemm_ares_kernel<0><<<256, 256, 0, stream>>>(xb, wqkvT, b_qkv, qkv);
  // attention
  attn_kv_kernel<<<dim3(32, NCHUNK), 256, 0, stream>>>(qkv, part);
  attn_softmax_kernel<<<32, 256, 0, stream>>>(part, attnb);
  // xf + residual + layernorm (MFMA)
  xf_ln_mfma_kernel<<<ROWS / 64, 256, 0, stream>>>(qkv, attnb, xb, x2b, hln, norm_g, norm_b);
  // mid = gelu(hln @ w_fc1 + b_fc1)   [32768 x 768]
  gemm_ares_kernel<1><<<256, 256, 0, stream>>>(hln, wfc1T, b_fc1, mid);
  // out = x2 + mid @ w_fc2 + b_fc2    [32768 x 256]
  fc2_kernel<<<ROWS / 64, 256, 0, stream>>>(mid, wfc2T, b_fc2, x2b, (float*)d_out);
}